// Round 1
// baseline (99.967 us; speedup 1.0000x reference)
//
#include <hip/hip_runtime.h>
#include <math.h>

static constexpr int M = 4096;   // batch rows
static constexpr int C = 512;    // classes
static constexpr int D = 128;    // feature dim
static constexpr float ALPHA = 0.5f;

// ---------------- workspace layout (bytes) ----------------
// label    : int[M]        @ 0        (16384)
// cnt      : float[C]      @ 16384    (2048)
// sumx     : float[C*D]    @ 18432    (262144)
// d_pos    : float[M]      @ 280576   (16384)
// loss_sum : float[M]      @ 296960   (16384)
// total 313344 bytes
static constexpr size_t WS_LABEL   = 0;
static constexpr size_t WS_CNT     = 16384;
static constexpr size_t WS_SUMX    = 18432;
static constexpr size_t WS_DPOS    = 280576;
static constexpr size_t WS_LSUM    = 296960;
static constexpr size_t WS_TOTAL   = 313344;

// ---- kernel 1: per-row label + per-class count and x-row sums ----
// one wave (64 lanes) per row; 4 rows per 256-thread block
__global__ __launch_bounds__(256) void k_label(
    const float* __restrict__ onehot, const float* __restrict__ x0,
    int* __restrict__ label, float* __restrict__ cnt, float* __restrict__ sumx)
{
    int gtid = blockIdx.x * 256 + threadIdx.x;
    int row  = gtid >> 6;
    int lane = threadIdx.x & 63;
    if (row >= M) return;

    const float4* oh = reinterpret_cast<const float4*>(onehot + (size_t)row * C);
    float4 a = oh[lane * 2 + 0];
    float4 b = oh[lane * 2 + 1];
    int lbl = -1;
    if (a.x > 0.5f) lbl = lane * 8 + 0;
    if (a.y > 0.5f) lbl = lane * 8 + 1;
    if (a.z > 0.5f) lbl = lane * 8 + 2;
    if (a.w > 0.5f) lbl = lane * 8 + 3;
    if (b.x > 0.5f) lbl = lane * 8 + 4;
    if (b.y > 0.5f) lbl = lane * 8 + 5;
    if (b.z > 0.5f) lbl = lane * 8 + 6;
    if (b.w > 0.5f) lbl = lane * 8 + 7;
    #pragma unroll
    for (int off = 32; off > 0; off >>= 1)
        lbl = max(lbl, __shfl_xor(lbl, off));

    if (lane == 0) {
        label[row] = lbl;
        atomicAdd(&cnt[lbl], 1.0f);
    }
    // accumulate this row of x0 into sumx[lbl]
    float2 xv = reinterpret_cast<const float2*>(x0 + (size_t)row * D)[lane];
    atomicAdd(&sumx[lbl * D + lane * 2 + 0], xv.x);
    atomicAdd(&sumx[lbl * D + lane * 2 + 1], xv.y);
}

// ---- kernel 2: new_centers = centers - ALPHA*(cnt*c - sumx)/(cnt+1) ----
__global__ __launch_bounds__(256) void k_newc(
    const float* __restrict__ centers, const float* __restrict__ cnt,
    const float* __restrict__ sumx, float* __restrict__ out_nc)
{
    int idx = blockIdx.x * 256 + threadIdx.x;   // 0 .. C*D-1
    int c = idx >> 7;                           // /D
    float n   = cnt[c];
    float ctr = centers[idx];
    out_nc[idx] = ctr - ALPHA * (n * ctr - sumx[idx]) / (n + 1.0f);
}

// ---- kernel 3: fused L1-distance tile + exp-sum + positive-distance pick ----
// grid: 64 m-tiles x 8 c-chunks = 512 blocks, 256 threads.
// Each thread: 4 m x 4 c register accumulators; LDS tiles stored transposed
// ([d][m] / [d][c]) with +4 pad (keeps float4 alignment, spreads banks).
__global__ __launch_bounds__(256) void k_dist(
    const float* __restrict__ x0, const float* __restrict__ centers,
    const int* __restrict__ label,
    float* __restrict__ d_pos, float* __restrict__ loss_sum)
{
    constexpr int BM = 64, BC = 64, DK = 64, STR = 68;
    __shared__ float xs[DK][STR];
    __shared__ float cs[DK][STR];
    __shared__ float rowsum[BM];

    int tid = threadIdx.x;
    int mb = blockIdx.x & 63;   // m tile
    int cb = blockIdx.x >> 6;   // c chunk
    int m0 = mb * BM, c0 = cb * BC;
    int tx = tid & 15;          // -> 4 c each
    int ty = tid >> 4;          // -> 4 m each

    float acc[4][4];
    #pragma unroll
    for (int i = 0; i < 4; i++)
        #pragma unroll
        for (int j = 0; j < 4; j++) acc[i][j] = 0.f;

    int lrow = tid >> 2;   // 0..63 : row of the staged tile
    int dg   = tid & 3;    // 0..3  : 16-d group

    for (int dc = 0; dc < 2; ++dc) {
        int d0 = dc * DK;
        __syncthreads();   // protect LDS from previous iteration's readers
        // stage x tile transposed: xs[d][m]
        {
            const float4* p = reinterpret_cast<const float4*>(
                x0 + (size_t)(m0 + lrow) * D + d0 + dg * 16);
            float4 v0 = p[0], v1 = p[1], v2 = p[2], v3 = p[3];
            float f[16] = {v0.x,v0.y,v0.z,v0.w, v1.x,v1.y,v1.z,v1.w,
                           v2.x,v2.y,v2.z,v2.w, v3.x,v3.y,v3.z,v3.w};
            int db = dg * 16;
            #pragma unroll
            for (int k = 0; k < 16; ++k) xs[db + k][lrow] = f[k];
        }
        // stage centers tile transposed: cs[d][c]
        {
            const float4* p = reinterpret_cast<const float4*>(
                centers + (size_t)(c0 + lrow) * D + d0 + dg * 16);
            float4 v0 = p[0], v1 = p[1], v2 = p[2], v3 = p[3];
            float f[16] = {v0.x,v0.y,v0.z,v0.w, v1.x,v1.y,v1.z,v1.w,
                           v2.x,v2.y,v2.z,v2.w, v3.x,v3.y,v3.z,v3.w};
            int db = dg * 16;
            #pragma unroll
            for (int k = 0; k < 16; ++k) cs[db + k][lrow] = f[k];
        }
        __syncthreads();

        #pragma unroll 8
        for (int d = 0; d < DK; ++d) {
            float4 xv = *reinterpret_cast<const float4*>(&xs[d][ty * 4]);
            float4 cv = *reinterpret_cast<const float4*>(&cs[d][tx * 4]);
            float xa[4] = {xv.x, xv.y, xv.z, xv.w};
            float ca[4] = {cv.x, cv.y, cv.z, cv.w};
            #pragma unroll
            for (int i = 0; i < 4; i++)
                #pragma unroll
                for (int j = 0; j < 4; j++)
                    acc[i][j] += fabsf(xa[i] - ca[j]);   // v_sub + v_add(|mod|)
        }
    }

    // epilogue: positive-class distance + partial exp-sums
    if (tid < BM) rowsum[tid] = 0.f;
    int lbls[4];
    #pragma unroll
    for (int i = 0; i < 4; i++) lbls[i] = label[m0 + ty * 4 + i];
    __syncthreads();

    #pragma unroll
    for (int i = 0; i < 4; i++) {
        float ps = 0.f;
        #pragma unroll
        for (int j = 0; j < 4; j++) {
            int cg = c0 + tx * 4 + j;
            float dist = acc[i][j];
            if (cg == lbls[i]) {
                d_pos[m0 + ty * 4 + i] = dist;   // unique writer per m
            } else {
                ps += expf(-dist);
            }
        }
        atomicAdd(&rowsum[ty * 4 + i], ps);
    }
    __syncthreads();
    if (tid < BM) atomicAdd(&loss_sum[m0 + tid], rowsum[tid]);
}

// ---- kernel 4: loss[m] = d_pos[m] + log(1 + sum_neg_exp[m]) ----
__global__ __launch_bounds__(256) void k_fin(
    const float* __restrict__ d_pos, const float* __restrict__ loss_sum,
    float* __restrict__ loss_out)
{
    int m = blockIdx.x * 256 + threadIdx.x;
    if (m < M) loss_out[m] = d_pos[m] + log1pf(loss_sum[m]);
}

extern "C" void kernel_launch(void* const* d_in, const int* in_sizes, int n_in,
                              void* d_out, int out_size, void* d_ws, size_t ws_size,
                              hipStream_t stream)
{
    const float* x0      = (const float*)d_in[0];   // (M, D)
    const float* onehot  = (const float*)d_in[1];   // (M, C)
    const float* centers = (const float*)d_in[2];   // (C, D)
    float* out = (float*)d_out;                     // [0..M) loss, [M..M+C*D) new_centers

    char* ws = (char*)d_ws;
    int*   label    = (int*)  (ws + WS_LABEL);
    float* cnt      = (float*)(ws + WS_CNT);
    float* sumx     = (float*)(ws + WS_SUMX);
    float* d_pos    = (float*)(ws + WS_DPOS);
    float* loss_sum = (float*)(ws + WS_LSUM);

    hipMemsetAsync(d_ws, 0, WS_TOTAL, stream);
    k_label<<<M / 4, 256, 0, stream>>>(onehot, x0, label, cnt, sumx);
    k_newc <<<(C * D) / 256, 256, 0, stream>>>(centers, cnt, sumx, out + M);
    k_dist <<<512, 256, 0, stream>>>(x0, centers, label, d_pos, loss_sum);
    k_fin  <<<(M + 255) / 256, 256, 0, stream>>>(d_pos, loss_sum, out);
}

// Round 2
// 92.775 us; speedup vs baseline: 1.0775x; 1.0775x over previous
//
#include <hip/hip_runtime.h>
#include <math.h>

static constexpr int M = 4096;   // batch rows
static constexpr int C = 512;    // classes
static constexpr int D = 128;    // feature dim
static constexpr float ALPHA = 0.5f;

// ---------------- workspace layout (bytes) ----------------
// label     : int[M]       @ 0        (16384)   fully written by k_label
// d_pos     : float[M]     @ 16384    (16384)   fully written by k_dist
// loss_part : float[M*8]   @ 32768    (131072)  fully written by k_dist
// -> no memset needed; every cell has exactly one writer.
static constexpr size_t WS_LABEL = 0;
static constexpr size_t WS_DPOS  = 16384;
static constexpr size_t WS_LPART = 32768;

// ---- kernel 1: per-row argmax of onehot -> label[M] ----
// one wave per row; 4 rows per 256-thread block; no atomics
__global__ __launch_bounds__(256) void k_label(
    const float* __restrict__ onehot, int* __restrict__ label)
{
    int gtid = blockIdx.x * 256 + threadIdx.x;
    int row  = gtid >> 6;
    int lane = threadIdx.x & 63;
    if (row >= M) return;

    const float4* oh = reinterpret_cast<const float4*>(onehot + (size_t)row * C);
    float4 a = oh[lane * 2 + 0];
    float4 b = oh[lane * 2 + 1];
    int lbl = -1;
    if (a.x > 0.5f) lbl = lane * 8 + 0;
    if (a.y > 0.5f) lbl = lane * 8 + 1;
    if (a.z > 0.5f) lbl = lane * 8 + 2;
    if (a.w > 0.5f) lbl = lane * 8 + 3;
    if (b.x > 0.5f) lbl = lane * 8 + 4;
    if (b.y > 0.5f) lbl = lane * 8 + 5;
    if (b.z > 0.5f) lbl = lane * 8 + 6;
    if (b.w > 0.5f) lbl = lane * 8 + 7;
    #pragma unroll
    for (int off = 32; off > 0; off >>= 1)
        lbl = max(lbl, __shfl_xor(lbl, off));
    if (lane == 0) label[row] = lbl;
}

// ---- kernel 2: per-class center update (no atomics, no zero-init) ----
// block c: scan labels into an LDS member list, then 128 threads gather-sum
// the member x0 rows along d and write new_centers.
__global__ __launch_bounds__(256) void k_newc(
    const float* __restrict__ x0, const float* __restrict__ centers,
    const int* __restrict__ label, float* __restrict__ out_nc)
{
    __shared__ int lcount;
    __shared__ int list[1024];
    int c   = blockIdx.x;
    int tid = threadIdx.x;
    if (tid == 0) lcount = 0;
    __syncthreads();

    const int4* lab4 = reinterpret_cast<const int4*>(label);
    #pragma unroll
    for (int t = 0; t < 4; ++t) {
        int4 v   = lab4[tid + 256 * t];
        int base = (tid + 256 * t) * 4;
        if (v.x == c) { int k = atomicAdd(&lcount, 1); if (k < 1024) list[k] = base + 0; }
        if (v.y == c) { int k = atomicAdd(&lcount, 1); if (k < 1024) list[k] = base + 1; }
        if (v.z == c) { int k = atomicAdd(&lcount, 1); if (k < 1024) list[k] = base + 2; }
        if (v.w == c) { int k = atomicAdd(&lcount, 1); if (k < 1024) list[k] = base + 3; }
    }
    __syncthreads();

    int n = lcount;                        // == count of class c
    if (tid < D) {
        float s = 0.f;
        for (int i = 0; i < n; ++i)
            s += x0[(size_t)list[i] * D + tid];   // coalesced across tid
        float ctr = centers[c * D + tid];
        out_nc[c * D + tid] = ctr - ALPHA * ((float)n * ctr - s) / ((float)n + 1.0f);
    }
}

// ---- kernel 3: fused L1-distance tile + exp-sum partials + d_pos pick ----
// grid: 64 m-tiles x 8 c-chunks = 512 blocks, 256 threads.
// 4m x 4c register tile per thread; LDS tiles transposed ([d][m]/[d][c], +4 pad).
// Epilogue: shfl butterfly over the 16-lane tx group (intra-wave) -> one
// partial per (row, chunk) written to loss_part; d_pos has a unique writer.
__global__ __launch_bounds__(256) void k_dist(
    const float* __restrict__ x0, const float* __restrict__ centers,
    const int* __restrict__ label,
    float* __restrict__ d_pos, float* __restrict__ loss_part)
{
    constexpr int BM = 64, DK = 64, STR = 68;
    __shared__ float xs[DK][STR];
    __shared__ float cs[DK][STR];

    int tid = threadIdx.x;
    int mb = blockIdx.x & 63;   // m tile
    int cb = blockIdx.x >> 6;   // c chunk
    int m0 = mb * BM, c0 = cb * BM;
    int tx = tid & 15;          // -> 4 c each
    int ty = tid >> 4;          // -> 4 m each

    float acc[4][4];
    #pragma unroll
    for (int i = 0; i < 4; i++)
        #pragma unroll
        for (int j = 0; j < 4; j++) acc[i][j] = 0.f;

    int lrow = tid >> 2;   // 0..63 : row of the staged tile
    int dg   = tid & 3;    // 0..3  : 16-d group

    for (int dc = 0; dc < 2; ++dc) {
        int d0 = dc * DK;
        __syncthreads();   // protect LDS from previous iteration's readers
        {
            const float4* p = reinterpret_cast<const float4*>(
                x0 + (size_t)(m0 + lrow) * D + d0 + dg * 16);
            float4 v0 = p[0], v1 = p[1], v2 = p[2], v3 = p[3];
            float f[16] = {v0.x,v0.y,v0.z,v0.w, v1.x,v1.y,v1.z,v1.w,
                           v2.x,v2.y,v2.z,v2.w, v3.x,v3.y,v3.z,v3.w};
            int db = dg * 16;
            #pragma unroll
            for (int k = 0; k < 16; ++k) xs[db + k][lrow] = f[k];
        }
        {
            const float4* p = reinterpret_cast<const float4*>(
                centers + (size_t)(c0 + lrow) * D + d0 + dg * 16);
            float4 v0 = p[0], v1 = p[1], v2 = p[2], v3 = p[3];
            float f[16] = {v0.x,v0.y,v0.z,v0.w, v1.x,v1.y,v1.z,v1.w,
                           v2.x,v2.y,v2.z,v2.w, v3.x,v3.y,v3.z,v3.w};
            int db = dg * 16;
            #pragma unroll
            for (int k = 0; k < 16; ++k) cs[db + k][lrow] = f[k];
        }
        __syncthreads();

        #pragma unroll 8
        for (int d = 0; d < DK; ++d) {
            float4 xv = *reinterpret_cast<const float4*>(&xs[d][ty * 4]);
            float4 cv = *reinterpret_cast<const float4*>(&cs[d][tx * 4]);
            float xa[4] = {xv.x, xv.y, xv.z, xv.w};
            float ca[4] = {cv.x, cv.y, cv.z, cv.w};
            #pragma unroll
            for (int i = 0; i < 4; i++)
                #pragma unroll
                for (int j = 0; j < 4; j++)
                    acc[i][j] += fabsf(xa[i] - ca[j]);   // v_sub + v_add(|mod|)
        }
    }

    // epilogue: positive-class distance + per-chunk exp-sum partials
    int lbls[4];
    #pragma unroll
    for (int i = 0; i < 4; i++) lbls[i] = label[m0 + ty * 4 + i];

    #pragma unroll
    for (int i = 0; i < 4; i++) {
        float ps = 0.f;
        #pragma unroll
        for (int j = 0; j < 4; j++) {
            int cg = c0 + tx * 4 + j;
            float dist = acc[i][j];
            if (cg == lbls[i]) {
                d_pos[m0 + ty * 4 + i] = dist;   // unique writer per m
            } else {
                ps += __expf(-dist);
            }
        }
        // butterfly over the 16-lane tx group (stays inside one wave)
        #pragma unroll
        for (int off = 8; off > 0; off >>= 1)
            ps += __shfl_xor(ps, off);
        if (tx == 0)
            loss_part[(size_t)(m0 + ty * 4 + i) * 8 + cb] = ps;
    }
}

// ---- kernel 4: loss[m] = d_pos[m] + log1p(sum of 8 chunk partials) ----
__global__ __launch_bounds__(256) void k_fin(
    const float* __restrict__ d_pos, const float* __restrict__ loss_part,
    float* __restrict__ loss_out)
{
    int m = blockIdx.x * 256 + threadIdx.x;
    if (m >= M) return;
    const float4* p = reinterpret_cast<const float4*>(loss_part + (size_t)m * 8);
    float4 a = p[0], b = p[1];
    float s = (a.x + a.y) + (a.z + a.w) + (b.x + b.y) + (b.z + b.w);
    loss_out[m] = d_pos[m] + log1pf(s);
}

extern "C" void kernel_launch(void* const* d_in, const int* in_sizes, int n_in,
                              void* d_out, int out_size, void* d_ws, size_t ws_size,
                              hipStream_t stream)
{
    const float* x0      = (const float*)d_in[0];   // (M, D)
    const float* onehot  = (const float*)d_in[1];   // (M, C)
    const float* centers = (const float*)d_in[2];   // (C, D)
    float* out = (float*)d_out;                     // [0..M) loss, [M..) new_centers

    char* ws = (char*)d_ws;
    int*   label     = (int*)  (ws + WS_LABEL);
    float* d_pos     = (float*)(ws + WS_DPOS);
    float* loss_part = (float*)(ws + WS_LPART);

    k_label<<<M / 4, 256, 0, stream>>>(onehot, label);
    k_newc <<<C,     256, 0, stream>>>(x0, centers, label, out + M);
    k_dist <<<512,   256, 0, stream>>>(x0, centers, label, d_pos, loss_part);
    k_fin  <<<M / 256, 256, 0, stream>>>(d_pos, loss_part, out);
}